// Round 7
// baseline (174.178 us; speedup 1.0000x reference)
//
#include <hip/hip_runtime.h>
#include <cstddef>
#include <cstdint>

// Problem constants (B,N,H) = (8,256,64)
constexpr int Bv = 8, Nv = 256, Hv = 64;
constexpr int ROWS = Bv * Nv;            // 2048
constexpr float INV_EDGE_CNT = 1.0f / (8.0f * 256.0f * 256.0f);
constexpr float INV_NODE_CNT = 1.0f / 2048.0f;
constexpr float EPSBN = 1e-5f;

// ws layout (float offsets)
constexpr size_t WS_VXE  = 0;          // [2048*64] PACKED [b][jt][t][lane][4]
constexpr size_t WS_VXN  = 131072;     // [2048*64] PACKED
constexpr size_t WS_UX   = 262144;     // [2048*64] linear [r][c]
constexpr size_t WS_AGG  = 393216;     // [2048*64] linear [r][c]
constexpr size_t WS_ESUM = 524288;     // [64] -> k_node folds to edge-BN scale
constexpr size_t WS_ESQ  = 524352;     // [64] -> k_node folds to edge-BN shift
constexpr size_t WS_ETMP = 524416;     // bf16[2048*256*64] = 67MB (if ws fits)
constexpr size_t ETMP_ELEMS = (size_t)ROWS * Nv * Hv;   // 33554432

typedef __bf16 bf16x8 __attribute__((ext_vector_type(8)));
typedef __bf16 bf16x4 __attribute__((ext_vector_type(4)));
typedef float  f32x4  __attribute__((ext_vector_type(4)));

__device__ __forceinline__ float4 ld4(const float* p) {
  return *reinterpret_cast<const float4*>(p);
}

__device__ __forceinline__ bf16x8 cvt8(float4 a, float4 b) {
  bf16x8 r;
  r[0] = (__bf16)a.x; r[1] = (__bf16)a.y; r[2] = (__bf16)a.z; r[3] = (__bf16)a.w;
  r[4] = (__bf16)b.x; r[5] = (__bf16)b.y; r[6] = (__bf16)b.z; r[7] = (__bf16)b.w;
  return r;
}

// async global->LDS 16B copy: lds dst is wave-uniform base + lane*16
__device__ __forceinline__ void async_cp16(const float* src, float* ldsDst) {
  __builtin_amdgcn_global_load_lds(
      (__attribute__((address_space(1))) void*)src,
      (__attribute__((address_space(3))) void*)ldsDst, 16, 0, 0);
}

// stage one 16-row j-tile (4KB) into sub-buffer s, source chunk-swizzled
__device__ __forceinline__ void stage_tile(const float* eTile, float* myBuf,
                                           int w, int lane, int s, int tt) {
#pragma unroll
  for (int k = 0; k < 4; ++k) {
    const int m  = k * 64 + lane;
    const int rl = m >> 4;            // 0..15
    const int pp = m & 15;
    const int cc = pp ^ (rl & 7);
    async_cp16(eTile + (size_t)(w * 64 + tt * 16 + rl) * 64 + cc * 4,
               myBuf + s * 1024 + k * 256);
  }
}

#define DOT4(acc, a, b) \
  acc = fmaf((a).x, (b).x, fmaf((a).y, (b).y, fmaf((a).z, (b).z, fmaf((a).w, (b).w, acc))))

// ---------------------------------------------------------------------------
// Linears: Vxe / Vxn written PACKED for the edge-kernel epilogue lane order;
// Ux written linear for k_node. Thread = (row, t, g) -> 4 channels.
__global__ __launch_bounds__(256) void k_lin(
    const float* __restrict__ x,
    const float* __restrict__ VeW, const float* __restrict__ Veb,
    const float* __restrict__ UnW, const float* __restrict__ Unb,
    const float* __restrict__ VnW, const float* __restrict__ Vnb,
    float* __restrict__ ws)
{
  const int idx = blockIdx.x * 256 + threadIdx.x;   // 32768 total
  const int r  = idx >> 4;           // row 0..2047
  const int tg = idx & 15;
  const int t  = tg >> 2, g = tg & 3;
  const int c0 = t * 16 + g * 4;

  const float4* x4 = (const float4*)(x + (size_t)r * 64);
  float a1[4] = {}, a2[4] = {}, a3[4] = {};
#pragma unroll
  for (int h = 0; h < 16; ++h) {
    float4 xv = x4[h];
#pragma unroll
    for (int cc = 0; cc < 4; ++cc) {
      float4 w1 = ld4(VeW + (size_t)(c0 + cc) * 64 + h * 4); DOT4(a1[cc], xv, w1);
      float4 w2 = ld4(UnW + (size_t)(c0 + cc) * 64 + h * 4); DOT4(a2[cc], xv, w2);
      float4 w3 = ld4(VnW + (size_t)(c0 + cc) * 64 + h * 4); DOT4(a3[cc], xv, w3);
    }
  }

  const int b = r >> 8, jt = (r >> 4) & 15, r16 = r & 15;
  const size_t pidx = ((size_t)((b * 16 + jt) * 4 + t)) * 256 + (g * 16 + r16) * 4;
  *(float4*)(&ws[WS_VXE + pidx]) =
      make_float4(a1[0] + Veb[c0], a1[1] + Veb[c0 + 1], a1[2] + Veb[c0 + 2], a1[3] + Veb[c0 + 3]);
  *(float4*)(&ws[WS_VXN + pidx]) =
      make_float4(a3[0] + Vnb[c0], a3[1] + Vnb[c0 + 1], a3[2] + Vnb[c0 + 2], a3[3] + Vnb[c0 + 3]);
  *(float4*)(&ws[WS_UX + (size_t)r * 64 + c0]) =
      make_float4(a2[0] + Unb[c0], a2[1] + Unb[c0 + 1], a2[2] + Unb[c0 + 2], a2[3] + Unb[c0 + 3]);
}

// ---------------------------------------------------------------------------
// Pass A: e_tmp = e@UeW^T + b + Vxe_i + Vxe_j via MFMA(W,e); wave w owns
// j-rows [64w,64w+64). Pipelined staging (vmcnt counted incl. 8 packed loads
// issued early); W held as bf16 in chunk-swizzled LDS (saves 32 VGPR).
// STORE_TMP: also store e_tmp (bf16, natural [j][c]) for the streaming pass C.
template<int STORE_TMP>
__global__ __launch_bounds__(256) void k_edgeA(
    const float* __restrict__ e,
    const float* __restrict__ UeW, const float* __restrict__ Ueb,
    float* __restrict__ ws, __bf16* __restrict__ etmp)
{
  __shared__ __align__(16) float eL[4 * 2048];     // 32KB staging (+reduce reuse)
  __shared__ __align__(16) __bf16 wLds[4096];      // 8KB W, chunk-swizzled

  const int tid  = threadIdx.x;
  const int lane = tid & 63;
  const int w    = tid >> 6;
  const int bi   = blockIdx.x;
  const int b    = bi >> 8;
  const int r16  = lane & 15;
  const int g    = lane >> 4;
  const int sw   = r16 & 7;

  const float* eTile = e + (size_t)bi * (Nv * Hv);
  float* myBuf = &eL[w * 2048];

  // stage W -> LDS (bf16, chunk p of row c stored at p ^ (c&7))
#pragma unroll
  for (int k = 0; k < 2; ++k) {
    const int m = tid * 2 + k;          // chunk 0..511
    const int c = m >> 3, p = m & 7;
    float4 lo = ld4(UeW + (size_t)c * 64 + p * 8);
    float4 hi = ld4(UeW + (size_t)c * 64 + p * 8 + 4);
    *(bf16x8*)(&wLds[(size_t)c * 64 + (size_t)(p ^ (c & 7)) * 8]) = cvt8(lo, hi);
  }
  __syncthreads();

  // prologue staging AFTER the barrier (barrier drains vmcnt)
  stage_tile(eTile, myBuf, w, lane, 0, 0);
  stage_tile(eTile, myBuf, w, lane, 1, 1);

  const float* VXEP = ws + WS_VXE;
  const float* VXNP = ws + WS_VXN;

  const int jti = (bi >> 4) & 15, r16i = bi & 15;
  float4 ueb4[4], vxei4[4];
#pragma unroll
  for (int t = 0; t < 4; ++t) {
    ueb4[t]  = ld4(Ueb + t * 16 + 4 * g);
    vxei4[t] = ld4(VXEP + ((size_t)((b * 16 + jti) * 4 + t)) * 256 + (g * 16 + r16i) * 4);
  }

  float sS[4][4] = {}, sQ[4][4] = {}, sA[4][4] = {};

#pragma unroll
  for (int p = 0; p < 4; ++p) {
    // packed epilogue loads issued EARLY (counted: 8 in flight at the wait)
    const size_t pb = (size_t)((b * 16 + (w * 4 + p)) * 4);
    float4 vj4[4], vn4[4];
#pragma unroll
    for (int t = 0; t < 4; ++t) {
      vj4[t] = ld4(VXEP + (pb + t) * 256 + lane * 4);
      vn4[t] = ld4(VXNP + (pb + t) * 256 + lane * 4);
    }
    // W fragments from LDS (lgkm pipe; independent of staging)
    bf16x8 wF0[4], wF1[4];
#pragma unroll
    for (int t = 0; t < 4; ++t) {
      const int wr = (16 * t + r16) * 64;
      wF0[t] = *(const bf16x8*)(&wLds[wr + ((g ^ sw) << 3)]);
      wF1[t] = *(const bf16x8*)(&wLds[wr + (((4 + g) ^ sw) << 3)]);
    }

    // wait for tile p: outstanding = (tiles younger) *4 + 8 packed
    if (p < 3) asm volatile("s_waitcnt vmcnt(12)" ::: "memory");
    else       asm volatile("s_waitcnt vmcnt(8)"  ::: "memory");
    __builtin_amdgcn_sched_barrier(0);

    const float* rbase = myBuf + (p & 1) * 1024 + r16 * 64;
    float4 f0 = ld4(rbase + (((2 * g)     ^ sw) << 2));
    float4 f1 = ld4(rbase + (((2 * g + 1) ^ sw) << 2));
    float4 f2 = ld4(rbase + ((((2 * g)     ^ sw) + 8) << 2));
    float4 f3 = ld4(rbase + ((((2 * g + 1) ^ sw) + 8) << 2));
    bf16x8 aF0 = cvt8(f0, f1);
    bf16x8 aF1 = cvt8(f2, f3);

    __builtin_amdgcn_sched_barrier(0);
    if (p < 2) stage_tile(eTile, myBuf, w, lane, p & 1, p + 2);

    f32x4 acc[4];
#pragma unroll
    for (int t = 0; t < 4; ++t) {
      f32x4 z = {0.f, 0.f, 0.f, 0.f};
      acc[t] = __builtin_amdgcn_mfma_f32_16x16x32_bf16(wF0[t], aF0, z, 0, 0, 0);
      acc[t] = __builtin_amdgcn_mfma_f32_16x16x32_bf16(wF1[t], aF1, acc[t], 0, 0, 0);
    }

    const int jrow = w * 64 + p * 16 + r16;
#pragma unroll
    for (int t = 0; t < 4; ++t) {
      float vj[4] = {vj4[t].x, vj4[t].y, vj4[t].z, vj4[t].w};
      float vn[4] = {vn4[t].x, vn4[t].y, vn4[t].z, vn4[t].w};
      float ub[4] = {ueb4[t].x, ueb4[t].y, ueb4[t].z, ueb4[t].w};
      float vi[4] = {vxei4[t].x, vxei4[t].y, vxei4[t].z, vxei4[t].w};
      float tvv[4];
#pragma unroll
      for (int r = 0; r < 4; ++r) {
        float tv = acc[t][r] + ub[r] + vi[r] + vj[r];
        tvv[r] = tv;
        sS[t][r] += tv;
        sQ[t][r]  = fmaf(tv, tv, sQ[t][r]);
        float sg  = __builtin_amdgcn_rcpf(1.0f + __expf(-tv));
        sA[t][r]  = fmaf(sg, vn[r], sA[t][r]);
      }
      if (STORE_TMP) {
        bf16x4 ev;
        ev[0] = (__bf16)tvv[0]; ev[1] = (__bf16)tvv[1];
        ev[2] = (__bf16)tvv[2]; ev[3] = (__bf16)tvv[3];
        *(bf16x4*)(&etmp[((size_t)bi * 256 + jrow) * 64 + t * 16 + 4 * g]) = ev;
      }
    }
  }

  // reduce over the 16 j-lanes (bits 0..3 of lane)
#pragma unroll
  for (int t = 0; t < 4; ++t)
#pragma unroll
    for (int r = 0; r < 4; ++r) {
#pragma unroll
      for (int m = 1; m < 16; m <<= 1) {
        sS[t][r] += __shfl_xor(sS[t][r], m);
        sQ[t][r] += __shfl_xor(sQ[t][r], m);
        sA[t][r] += __shfl_xor(sA[t][r], m);
      }
    }

  // per-wave partials into the wave's own (now idle) staging region
  if (r16 == 0) {
#pragma unroll
    for (int t = 0; t < 4; ++t) {
      const int cb = t * 16 + 4 * g;
      *(float4*)(&myBuf[cb])       = make_float4(sA[t][0], sA[t][1], sA[t][2], sA[t][3]);
      *(float4*)(&myBuf[256 + cb]) = make_float4(sS[t][0], sS[t][1], sS[t][2], sS[t][3]);
      *(float4*)(&myBuf[512 + cb]) = make_float4(sQ[t][0], sQ[t][1], sQ[t][2], sQ[t][3]);
    }
  }
  __syncthreads();
  if (tid < 64) {
    const int c = tid;
    float a  = eL[c]       + eL[2048 + c]       + eL[4096 + c]       + eL[6144 + c];
    ws[WS_AGG + (size_t)bi * 64 + c] = a;
    float s  = eL[256 + c] + eL[2048 + 256 + c] + eL[4096 + 256 + c] + eL[6144 + 256 + c];
    atomicAdd(&ws[WS_ESUM + c], s);
    float qv = eL[512 + c] + eL[2048 + 512 + c] + eL[4096 + 512 + c] + eL[6144 + 512 + c];
    atomicAdd(&ws[WS_ESQ + c], qv);
  }
}

// ---------------------------------------------------------------------------
// Node path: x_tmp = Ux + agg ; BN over (B,N) per channel ; relu + residual.
// Thread 0 folds the edge-BN stats into scale/shift (in-place).
__global__ __launch_bounds__(256) void k_node(
    const float* __restrict__ x,
    const float* __restrict__ bnng, const float* __restrict__ bnnb,
    const float* __restrict__ bneg, const float* __restrict__ bneb,
    float* __restrict__ ws, float* __restrict__ xOut)
{
  const int c = blockIdx.x;
  const int tid = threadIdx.x;

  if (tid == 0) {
    float mean = ws[WS_ESUM + c] * INV_EDGE_CNT;
    float var  = ws[WS_ESQ  + c] * INV_EDGE_CNT - mean * mean;
    float sc = rsqrtf(var + EPSBN) * bneg[c];
    ws[WS_ESUM + c] = sc;
    ws[WS_ESQ  + c] = bneb[c] - mean * sc;
  }

  const float* Ux  = ws + WS_UX;
  const float* agg = ws + WS_AGG;

  float v[8];
  float s = 0.f, q = 0.f;
#pragma unroll
  for (int k = 0; k < 8; ++k) {
    int r = tid + 256 * k;
    float t = Ux[(size_t)r * 64 + c] + agg[(size_t)r * 64 + c];
    v[k] = t;
    s += t;
    q = fmaf(t, t, q);
  }
#pragma unroll
  for (int m = 1; m < 64; m <<= 1) {
    s += __shfl_xor(s, m);
    q += __shfl_xor(q, m);
  }
  __shared__ float ss[4], qq[4];
  int w = tid >> 6;
  if ((tid & 63) == 0) { ss[w] = s; qq[w] = q; }
  __syncthreads();
  float S = ss[0] + ss[1] + ss[2] + ss[3];
  float Q = qq[0] + qq[1] + qq[2] + qq[3];
  float mean = S * INV_NODE_CNT;
  float var  = Q * INV_NODE_CNT - mean * mean;
  float scv = rsqrtf(var + EPSBN) * bnng[c];
  float shv = bnnb[c] - mean * scv;
#pragma unroll
  for (int k = 0; k < 8; ++k) {
    int r = tid + 256 * k;
    float y = fmaf(v[k], scv, shv);
    xOut[(size_t)r * 64 + c] = fmaxf(y, 0.f) + x[(size_t)r * 64 + c];
  }
}

// ---------------------------------------------------------------------------
// Pass C (streaming): e_new = relu(e_tmp*sc + sh) + e. Fully coalesced,
// latency-tolerant; no MFMA, no staging. 2048 blocks x 256 thr x 8 iters x 8.
__global__ __launch_bounds__(256) void k_edgeC2(
    const float* __restrict__ e, const __bf16* __restrict__ etmp,
    const float* __restrict__ ws, float* __restrict__ eOut)
{
  const int tid = blockIdx.x * 256 + threadIdx.x;     // 524288
  const int c0 = (tid & 7) * 8;
  const float4 scA = ld4(ws + WS_ESUM + c0), scB = ld4(ws + WS_ESUM + c0 + 4);
  const float4 shA = ld4(ws + WS_ESQ  + c0), shB = ld4(ws + WS_ESQ  + c0 + 4);

#pragma unroll
  for (int it = 0; it < 8; ++it) {
    const size_t base = ((size_t)it * 524288 + tid) * 8;
    bf16x8 t8 = *(const bf16x8*)(&etmp[base]);
    float4 e0 = ld4(e + base), e1 = ld4(e + base + 4);
    float4 o0, o1;
    o0.x = fmaxf(fmaf((float)t8[0], scA.x, shA.x), 0.f) + e0.x;
    o0.y = fmaxf(fmaf((float)t8[1], scA.y, shA.y), 0.f) + e0.y;
    o0.z = fmaxf(fmaf((float)t8[2], scA.z, shA.z), 0.f) + e0.z;
    o0.w = fmaxf(fmaf((float)t8[3], scA.w, shA.w), 0.f) + e0.w;
    o1.x = fmaxf(fmaf((float)t8[4], scB.x, shB.x), 0.f) + e1.x;
    o1.y = fmaxf(fmaf((float)t8[5], scB.y, shB.y), 0.f) + e1.y;
    o1.z = fmaxf(fmaf((float)t8[6], scB.z, shB.z), 0.f) + e1.z;
    o1.w = fmaxf(fmaf((float)t8[7], scB.w, shB.w), 0.f) + e1.w;
    *(float4*)(eOut + base)     = o0;
    *(float4*)(eOut + base + 4) = o1;
  }
}

// ---------------------------------------------------------------------------
// Pass C fallback (ws too small for e_tmp): recompute via MFMA (r6 version).
__global__ __launch_bounds__(256) void k_edgeC(
    const float* __restrict__ e,
    const float* __restrict__ UeW, const float* __restrict__ Ueb,
    const float* __restrict__ ws, float* __restrict__ eOut)
{
  __shared__ __align__(16) float eL[4 * 2048];

  const int tid  = threadIdx.x;
  const int lane = tid & 63;
  const int w    = tid >> 6;
  const int bi   = blockIdx.x;
  const int b    = bi >> 8;
  const int r16  = lane & 15;
  const int g    = lane >> 4;
  const int sw   = r16 & 7;

  const float* eTile = e + (size_t)bi * (Nv * Hv);
  float* myBuf = &eL[w * 2048];
  float* oTile = eOut + (size_t)bi * (Nv * Hv);

  bf16x8 wF0[4], wF1[4];
#pragma unroll
  for (int t = 0; t < 4; ++t) {
    const float* wrow = UeW + (size_t)(t * 16 + r16) * 64 + 8 * g;
    wF0[t] = cvt8(ld4(wrow),      ld4(wrow + 4));
    wF1[t] = cvt8(ld4(wrow + 32), ld4(wrow + 36));
  }

  const float* VXEP = ws + WS_VXE;
  const int jti = (bi >> 4) & 15, r16i = bi & 15;
  float4 ueb4[4], vxei4[4], sc4[4], sh4[4];
#pragma unroll
  for (int t = 0; t < 4; ++t) {
    ueb4[t]  = ld4(Ueb + t * 16 + 4 * g);
    vxei4[t] = ld4(VXEP + ((size_t)((b * 16 + jti) * 4 + t)) * 256 + (g * 16 + r16i) * 4);
    sc4[t]   = ld4(ws + WS_ESUM + t * 16 + 4 * g);
    sh4[t]   = ld4(ws + WS_ESQ  + t * 16 + 4 * g);
  }

  stage_tile(eTile, myBuf, w, lane, 0, 0);
  stage_tile(eTile, myBuf, w, lane, 1, 1);

#pragma unroll
  for (int p = 0; p < 4; ++p) {
    if (p < 3) asm volatile("s_waitcnt vmcnt(4)" ::: "memory");
    else       asm volatile("s_waitcnt vmcnt(0)" ::: "memory");

    const int j = w * 64 + p * 16 + r16;
    const size_t pb = (size_t)((b * 16 + (w * 4 + p)) * 4);
    float4 vj4[4];
#pragma unroll
    for (int t = 0; t < 4; ++t)
      vj4[t] = ld4(VXEP + (pb + t) * 256 + lane * 4);

    const float* rbase = myBuf + (p & 1) * 1024 + r16 * 64;
    float4 f0 = ld4(rbase + (((2 * g)     ^ sw) << 2));
    float4 f1 = ld4(rbase + (((2 * g + 1) ^ sw) << 2));
    float4 f2 = ld4(rbase + ((((2 * g)     ^ sw) + 8) << 2));
    float4 f3 = ld4(rbase + ((((2 * g + 1) ^ sw) + 8) << 2));
    bf16x8 aF0 = cvt8(f0, f1);
    bf16x8 aF1 = cvt8(f2, f3);

    f32x4 acc[4];
#pragma unroll
    for (int t = 0; t < 4; ++t) {
      f32x4 z = {0.f, 0.f, 0.f, 0.f};
      acc[t] = __builtin_amdgcn_mfma_f32_16x16x32_bf16(wF0[t], aF0, z, 0, 0, 0);
      acc[t] = __builtin_amdgcn_mfma_f32_16x16x32_bf16(wF1[t], aF1, acc[t], 0, 0, 0);
    }

#pragma unroll
    for (int t = 0; t < 4; ++t) {
      float4 res4 = ld4(rbase + (((4 * t + g) ^ sw) << 2));
      float vj[4] = {vj4[t].x, vj4[t].y, vj4[t].z, vj4[t].w};
      float rs[4] = {res4.x, res4.y, res4.z, res4.w};
      float ub[4] = {ueb4[t].x, ueb4[t].y, ueb4[t].z, ueb4[t].w};
      float vi[4] = {vxei4[t].x, vxei4[t].y, vxei4[t].z, vxei4[t].w};
      float sc[4] = {sc4[t].x, sc4[t].y, sc4[t].z, sc4[t].w};
      float sh[4] = {sh4[t].x, sh4[t].y, sh4[t].z, sh4[t].w};
      float out[4];
#pragma unroll
      for (int r = 0; r < 4; ++r) {
        float tv = acc[t][r] + ub[r] + vi[r] + vj[r];
        float y  = fmaf(tv, sc[r], sh[r]);
        out[r] = fmaxf(y, 0.f) + rs[r];
      }
      *(float4*)(oTile + (size_t)j * 64 + t * 16 + 4 * g) =
          make_float4(out[0], out[1], out[2], out[3]);
    }

    __builtin_amdgcn_sched_barrier(0);
    if (p < 2) stage_tile(eTile, myBuf, w, lane, p & 1, p + 2);
  }
}

// ---------------------------------------------------------------------------
extern "C" void kernel_launch(void* const* d_in, const int* in_sizes, int n_in,
                              void* d_out, int out_size, void* d_ws, size_t ws_size,
                              hipStream_t stream)
{
  const float* x    = (const float*)d_in[0];
  const float* e    = (const float*)d_in[1];
  const float* UeW  = (const float*)d_in[2];
  const float* Ueb  = (const float*)d_in[3];
  const float* VeW  = (const float*)d_in[4];
  const float* Veb  = (const float*)d_in[5];
  const float* UnW  = (const float*)d_in[6];
  const float* Unb  = (const float*)d_in[7];
  const float* VnW  = (const float*)d_in[8];
  const float* Vnb  = (const float*)d_in[9];
  const float* bneg = (const float*)d_in[10];
  const float* bneb = (const float*)d_in[11];
  const float* bnng = (const float*)d_in[12];
  const float* bnnb = (const float*)d_in[13];

  float* ws   = (float*)d_ws;
  float* xOut = (float*)d_out;
  float* eOut = (float*)d_out + (size_t)ROWS * Hv;
  __bf16* etmp = (__bf16*)(ws + WS_ETMP);

  const size_t needBytes = WS_ETMP * sizeof(float) + ETMP_ELEMS * sizeof(__bf16);
  const bool useTmp = ws_size >= needBytes;

  hipMemsetAsync(ws + WS_ESUM, 0, 128 * sizeof(float), stream);

  k_lin<<<128, 256, 0, stream>>>(x, VeW, Veb, UnW, Unb, VnW, Vnb, ws);
  if (useTmp) {
    k_edgeA<1><<<ROWS, 256, 0, stream>>>(e, UeW, Ueb, ws, etmp);
    k_node<<<Hv, 256, 0, stream>>>(x, bnng, bnnb, bneg, bneb, ws, xOut);
    k_edgeC2<<<2048, 256, 0, stream>>>(e, etmp, ws, eOut);
  } else {
    k_edgeA<0><<<ROWS, 256, 0, stream>>>(e, UeW, Ueb, ws, etmp);
    k_node<<<Hv, 256, 0, stream>>>(x, bnng, bnnb, bneg, bneb, ws, xOut);
    k_edgeC<<<ROWS, 256, 0, stream>>>(e, UeW, Ueb, ws, eOut);
  }
}

// Round 8
// 152.189 us; speedup vs baseline: 1.1445x; 1.1445x over previous
//
#include <hip/hip_runtime.h>
#include <cstddef>
#include <cstdint>

// Problem constants (B,N,H) = (8,256,64)
constexpr int Bv = 8, Nv = 256, Hv = 64;
constexpr int ROWS = Bv * Nv;            // 2048
constexpr float INV_EDGE_CNT = 1.0f / (8.0f * 256.0f * 256.0f);
constexpr float INV_NODE_CNT = 1.0f / 2048.0f;
constexpr float EPSBN = 1e-5f;

// ws layout (float offsets)
constexpr size_t WS_VXE  = 0;          // [2048*64] PACKED [b][jt][t][lane][4]
constexpr size_t WS_VXN  = 131072;     // [2048*64] PACKED
constexpr size_t WS_UX   = 262144;     // [2048*64] linear [r][c]
constexpr size_t WS_AGG  = 393216;     // [2048*64] linear [r][c]
constexpr size_t WS_ESUM = 524288;     // [64] -> k_node folds to edge-BN scale
constexpr size_t WS_ESQ  = 524352;     // [64] -> k_node folds to edge-BN shift

typedef __bf16 bf16x8 __attribute__((ext_vector_type(8)));
typedef float  f32x4  __attribute__((ext_vector_type(4)));

__device__ __forceinline__ float4 ld4(const float* p) {
  return *reinterpret_cast<const float4*>(p);
}

__device__ __forceinline__ bf16x8 cvt8(float4 a, float4 b) {
  bf16x8 r;
  r[0] = (__bf16)a.x; r[1] = (__bf16)a.y; r[2] = (__bf16)a.z; r[3] = (__bf16)a.w;
  r[4] = (__bf16)b.x; r[5] = (__bf16)b.y; r[6] = (__bf16)b.z; r[7] = (__bf16)b.w;
  return r;
}

// global tile load into regs (T14 issue-early half). Chunk-swizzled source:
// reg k holds e[row rl = (k*64+lane)>>4][chunk ((k*64+lane)&15) ^ (rl&7)].
__device__ __forceinline__ void load_tile_G(const float* eTile, int w, int lane,
                                            int tt, float4 G[4]) {
#pragma unroll
  for (int k = 0; k < 4; ++k) {
    const int m  = k * 64 + lane;
    const int rl = m >> 4;
    const int pp = m & 15;
    const int cc = pp ^ (rl & 7);
    G[k] = ld4(eTile + (size_t)(w * 64 + tt * 16 + rl) * 64 + cc * 4);
  }
}

// write-late half: linear LDS dst (mirrors the gload_lds layout)
__device__ __forceinline__ void write_tile_L(float* myBuf, int lane, int s,
                                             const float4 G[4]) {
#pragma unroll
  for (int k = 0; k < 4; ++k)
    *(float4*)(myBuf + s * 1024 + k * 256 + lane * 4) = G[k];
}

#define DOT4(acc, a, b) \
  acc = fmaf((a).x, (b).x, fmaf((a).y, (b).y, fmaf((a).z, (b).z, fmaf((a).w, (b).w, acc))))

// ---------------------------------------------------------------------------
// Linears: Vxe / Vxn written PACKED for the edge-kernel epilogue lane order;
// Ux written linear for k_node. Thread = (row, t, g) -> 4 channels.
__global__ __launch_bounds__(256) void k_lin(
    const float* __restrict__ x,
    const float* __restrict__ VeW, const float* __restrict__ Veb,
    const float* __restrict__ UnW, const float* __restrict__ Unb,
    const float* __restrict__ VnW, const float* __restrict__ Vnb,
    float* __restrict__ ws)
{
  const int idx = blockIdx.x * 256 + threadIdx.x;   // 32768 total
  const int r  = idx >> 4;           // row 0..2047
  const int tg = idx & 15;
  const int t  = tg >> 2, g = tg & 3;
  const int c0 = t * 16 + g * 4;

  const float4* x4 = (const float4*)(x + (size_t)r * 64);
  float a1[4] = {}, a2[4] = {}, a3[4] = {};
#pragma unroll
  for (int h = 0; h < 16; ++h) {
    float4 xv = x4[h];
#pragma unroll
    for (int cc = 0; cc < 4; ++cc) {
      float4 w1 = ld4(VeW + (size_t)(c0 + cc) * 64 + h * 4); DOT4(a1[cc], xv, w1);
      float4 w2 = ld4(UnW + (size_t)(c0 + cc) * 64 + h * 4); DOT4(a2[cc], xv, w2);
      float4 w3 = ld4(VnW + (size_t)(c0 + cc) * 64 + h * 4); DOT4(a3[cc], xv, w3);
    }
  }

  const int b = r >> 8, jt = (r >> 4) & 15, r16 = r & 15;
  const size_t pidx = ((size_t)((b * 16 + jt) * 4 + t)) * 256 + (g * 16 + r16) * 4;
  *(float4*)(&ws[WS_VXE + pidx]) =
      make_float4(a1[0] + Veb[c0], a1[1] + Veb[c0 + 1], a1[2] + Veb[c0 + 2], a1[3] + Veb[c0 + 3]);
  *(float4*)(&ws[WS_VXN + pidx]) =
      make_float4(a3[0] + Vnb[c0], a3[1] + Vnb[c0 + 1], a3[2] + Vnb[c0 + 2], a3[3] + Vnb[c0 + 3]);
  *(float4*)(&ws[WS_UX + (size_t)r * 64 + c0]) =
      make_float4(a2[0] + Unb[c0], a2[1] + Unb[c0 + 1], a2[2] + Unb[c0 + 2], a2[3] + Unb[c0 + 3]);
}

// ---------------------------------------------------------------------------
// Pass A: e_tmp = e@UeW^T + b + Vxe_i + Vxe_j via MFMA(W,e); wave w owns
// j-rows [64w,64w+64). Register-staged pipeline (NO global_load_lds — the
// compiler can't count its LDS dependence and inserts vmcnt(0) drains):
// tile p+2 global->regs and packed p+1 loads are issued during phase p,
// ds_write of tile p+2 at phase end. All waits compiler-counted.
__global__ __launch_bounds__(256) void k_edgeA(
    const float* __restrict__ e,
    const float* __restrict__ UeW, const float* __restrict__ Ueb,
    float* __restrict__ ws)
{
  __shared__ __align__(16) float eL[4 * 2048];     // 32KB tile dbuf (+reduce reuse)
  __shared__ __align__(16) __bf16 wLds[4096];      // 8KB W, chunk-swizzled

  const int tid  = threadIdx.x;
  const int lane = tid & 63;
  const int w    = tid >> 6;
  const int bi   = blockIdx.x;
  const int b    = bi >> 8;
  const int r16  = lane & 15;
  const int g    = lane >> 4;
  const int sw   = r16 & 7;

  const float* eTile = e + (size_t)bi * (Nv * Hv);
  float* myBuf = &eL[w * 2048];

  // stage W -> LDS (bf16, chunk p of row c stored at p ^ (c&7))
#pragma unroll
  for (int k = 0; k < 2; ++k) {
    const int m = tid * 2 + k;          // chunk 0..511
    const int c = m >> 3, p = m & 7;
    float4 lo = ld4(UeW + (size_t)c * 64 + p * 8);
    float4 hi = ld4(UeW + (size_t)c * 64 + p * 8 + 4);
    *(bf16x8*)(&wLds[(size_t)c * 64 + (size_t)(p ^ (c & 7)) * 8]) = cvt8(lo, hi);
  }

  const float* VXEP = ws + WS_VXE;
  const float* VXNP = ws + WS_VXN;

  const int jti = (bi >> 4) & 15, r16i = bi & 15;
  float4 ueb4[4], vxei4[4];
#pragma unroll
  for (int t = 0; t < 4; ++t) {
    ueb4[t]  = ld4(Ueb + t * 16 + 4 * g);
    vxei4[t] = ld4(VXEP + ((size_t)((b * 16 + jti) * 4 + t)) * 256 + (g * 16 + r16i) * 4);
  }

  // prologue: tiles 0,1 -> regs -> LDS ; packed phase-0 loads in flight
  float4 Ga[4], Gb[4];
  float4 Pj[2][4], Pn[2][4];
  load_tile_G(eTile, w, lane, 0, Ga);
  load_tile_G(eTile, w, lane, 1, Gb);
  {
    const size_t pb0 = (size_t)((b * 16 + (w * 4 + 0)) * 4);
#pragma unroll
    for (int t = 0; t < 4; ++t) {
      Pj[0][t] = ld4(VXEP + (pb0 + t) * 256 + lane * 4);
      Pn[0][t] = ld4(VXNP + (pb0 + t) * 256 + lane * 4);
    }
  }
  __syncthreads();                       // W ready (also covers wLds writes)
  write_tile_L(myBuf, lane, 0, Ga);
  write_tile_L(myBuf, lane, 1, Gb);

  float sS[4][4] = {}, sQ[4][4] = {}, sA[4][4] = {};

#pragma unroll
  for (int p = 0; p < 4; ++p) {
    // W fragments from LDS
    bf16x8 wF0[4], wF1[4];
#pragma unroll
    for (int t = 0; t < 4; ++t) {
      const int wr = (16 * t + r16) * 64;
      wF0[t] = *(const bf16x8*)(&wLds[wr + ((g ^ sw) << 3)]);
      wF1[t] = *(const bf16x8*)(&wLds[wr + (((4 + g) ^ sw) << 3)]);
    }
    // tile fragments from LDS (buffer p&1)
    const float* rbase = myBuf + (p & 1) * 1024 + r16 * 64;
    float4 f0 = ld4(rbase + (((2 * g)     ^ sw) << 2));
    float4 f1 = ld4(rbase + (((2 * g + 1) ^ sw) << 2));
    float4 f2 = ld4(rbase + ((((2 * g)     ^ sw) + 8) << 2));
    float4 f3 = ld4(rbase + ((((2 * g + 1) ^ sw) + 8) << 2));
    bf16x8 aF0 = cvt8(f0, f1);
    bf16x8 aF1 = cvt8(f2, f3);

    // prefetch: packed for p+1, tile p+2 (full phase in flight)
    if (p < 3) {
      const size_t pbn = (size_t)((b * 16 + (w * 4 + p + 1)) * 4);
#pragma unroll
      for (int t = 0; t < 4; ++t) {
        Pj[(p + 1) & 1][t] = ld4(VXEP + (pbn + t) * 256 + lane * 4);
        Pn[(p + 1) & 1][t] = ld4(VXNP + (pbn + t) * 256 + lane * 4);
      }
    }
    if (p < 2) load_tile_G(eTile, w, lane, p + 2, (p & 1) ? Gb : Ga);

    f32x4 acc[4];
#pragma unroll
    for (int t = 0; t < 4; ++t) {
      f32x4 z = {0.f, 0.f, 0.f, 0.f};
      acc[t] = __builtin_amdgcn_mfma_f32_16x16x32_bf16(wF0[t], aF0, z, 0, 0, 0);
      acc[t] = __builtin_amdgcn_mfma_f32_16x16x32_bf16(wF1[t], aF1, acc[t], 0, 0, 0);
    }

#pragma unroll
    for (int t = 0; t < 4; ++t) {
      float vj[4] = {Pj[p & 1][t].x, Pj[p & 1][t].y, Pj[p & 1][t].z, Pj[p & 1][t].w};
      float vn[4] = {Pn[p & 1][t].x, Pn[p & 1][t].y, Pn[p & 1][t].z, Pn[p & 1][t].w};
      float ub[4] = {ueb4[t].x, ueb4[t].y, ueb4[t].z, ueb4[t].w};
      float vi[4] = {vxei4[t].x, vxei4[t].y, vxei4[t].z, vxei4[t].w};
#pragma unroll
      for (int r = 0; r < 4; ++r) {
        float tv = acc[t][r] + ub[r] + vi[r] + vj[r];
        sS[t][r] += tv;
        sQ[t][r]  = fmaf(tv, tv, sQ[t][r]);
        float sg  = __builtin_amdgcn_rcpf(1.0f + __expf(-tv));
        sA[t][r]  = fmaf(sg, vn[r], sA[t][r]);
      }
    }

    // write tile p+2 into the buffer just consumed (read-before-write kept
    // by LDS alias ordering; write waits only on its own global loads)
    if (p < 2) write_tile_L(myBuf, lane, p & 1, (p & 1) ? Gb : Ga);
    __builtin_amdgcn_sched_barrier(0);
  }

  // reduce over the 16 j-lanes (bits 0..3 of lane)
#pragma unroll
  for (int t = 0; t < 4; ++t)
#pragma unroll
    for (int r = 0; r < 4; ++r) {
#pragma unroll
      for (int m = 1; m < 16; m <<= 1) {
        sS[t][r] += __shfl_xor(sS[t][r], m);
        sQ[t][r] += __shfl_xor(sQ[t][r], m);
        sA[t][r] += __shfl_xor(sA[t][r], m);
      }
    }

  // per-wave partials into the wave's own (now idle) staging region
  if (r16 == 0) {
#pragma unroll
    for (int t = 0; t < 4; ++t) {
      const int cb = t * 16 + 4 * g;
      *(float4*)(&myBuf[cb])       = make_float4(sA[t][0], sA[t][1], sA[t][2], sA[t][3]);
      *(float4*)(&myBuf[256 + cb]) = make_float4(sS[t][0], sS[t][1], sS[t][2], sS[t][3]);
      *(float4*)(&myBuf[512 + cb]) = make_float4(sQ[t][0], sQ[t][1], sQ[t][2], sQ[t][3]);
    }
  }
  __syncthreads();
  if (tid < 64) {
    const int c = tid;
    float a  = eL[c]       + eL[2048 + c]       + eL[4096 + c]       + eL[6144 + c];
    ws[WS_AGG + (size_t)bi * 64 + c] = a;
    float s  = eL[256 + c] + eL[2048 + 256 + c] + eL[4096 + 256 + c] + eL[6144 + 256 + c];
    atomicAdd(&ws[WS_ESUM + c], s);
    float qv = eL[512 + c] + eL[2048 + 512 + c] + eL[4096 + 512 + c] + eL[6144 + 512 + c];
    atomicAdd(&ws[WS_ESQ + c], qv);
  }
}

// ---------------------------------------------------------------------------
// Node path: x_tmp = Ux + agg ; BN over (B,N) per channel ; relu + residual.
// Thread 0 folds the edge-BN stats into scale/shift (in-place).
__global__ __launch_bounds__(256) void k_node(
    const float* __restrict__ x,
    const float* __restrict__ bnng, const float* __restrict__ bnnb,
    const float* __restrict__ bneg, const float* __restrict__ bneb,
    float* __restrict__ ws, float* __restrict__ xOut)
{
  const int c = blockIdx.x;
  const int tid = threadIdx.x;

  if (tid == 0) {
    float mean = ws[WS_ESUM + c] * INV_EDGE_CNT;
    float var  = ws[WS_ESQ  + c] * INV_EDGE_CNT - mean * mean;
    float sc = rsqrtf(var + EPSBN) * bneg[c];
    ws[WS_ESUM + c] = sc;
    ws[WS_ESQ  + c] = bneb[c] - mean * sc;
  }

  const float* Ux  = ws + WS_UX;
  const float* agg = ws + WS_AGG;

  float v[8];
  float s = 0.f, q = 0.f;
#pragma unroll
  for (int k = 0; k < 8; ++k) {
    int r = tid + 256 * k;
    float t = Ux[(size_t)r * 64 + c] + agg[(size_t)r * 64 + c];
    v[k] = t;
    s += t;
    q = fmaf(t, t, q);
  }
#pragma unroll
  for (int m = 1; m < 64; m <<= 1) {
    s += __shfl_xor(s, m);
    q += __shfl_xor(q, m);
  }
  __shared__ float ss[4], qq[4];
  int w = tid >> 6;
  if ((tid & 63) == 0) { ss[w] = s; qq[w] = q; }
  __syncthreads();
  float S = ss[0] + ss[1] + ss[2] + ss[3];
  float Q = qq[0] + qq[1] + qq[2] + qq[3];
  float mean = S * INV_NODE_CNT;
  float var  = Q * INV_NODE_CNT - mean * mean;
  float scv = rsqrtf(var + EPSBN) * bnng[c];
  float shv = bnnb[c] - mean * scv;
#pragma unroll
  for (int k = 0; k < 8; ++k) {
    int r = tid + 256 * k;
    float y = fmaf(v[k], scv, shv);
    xOut[(size_t)r * 64 + c] = fmaxf(y, 0.f) + x[(size_t)r * 64 + c];
  }
}

// ---------------------------------------------------------------------------
// Pass C: recompute e_tmp via MFMA (same register-staged pipeline), apply
// prefolded edge BN + relu + residual (residual from LDS), float4 stores.
__global__ __launch_bounds__(256) void k_edgeC(
    const float* __restrict__ e,
    const float* __restrict__ UeW, const float* __restrict__ Ueb,
    const float* __restrict__ ws, float* __restrict__ eOut)
{
  __shared__ __align__(16) float eL[4 * 2048];
  __shared__ __align__(16) __bf16 wLds[4096];

  const int tid  = threadIdx.x;
  const int lane = tid & 63;
  const int w    = tid >> 6;
  const int bi   = blockIdx.x;
  const int b    = bi >> 8;
  const int r16  = lane & 15;
  const int g    = lane >> 4;
  const int sw   = r16 & 7;

  const float* eTile = e + (size_t)bi * (Nv * Hv);
  float* myBuf = &eL[w * 2048];
  float* oTile = eOut + (size_t)bi * (Nv * Hv);

#pragma unroll
  for (int k = 0; k < 2; ++k) {
    const int m = tid * 2 + k;
    const int c = m >> 3, p = m & 7;
    float4 lo = ld4(UeW + (size_t)c * 64 + p * 8);
    float4 hi = ld4(UeW + (size_t)c * 64 + p * 8 + 4);
    *(bf16x8*)(&wLds[(size_t)c * 64 + (size_t)(p ^ (c & 7)) * 8]) = cvt8(lo, hi);
  }

  const float* VXEP = ws + WS_VXE;
  const int jti = (bi >> 4) & 15, r16i = bi & 15;
  float4 ueb4[4], vxei4[4], sc4[4], sh4[4];
#pragma unroll
  for (int t = 0; t < 4; ++t) {
    ueb4[t]  = ld4(Ueb + t * 16 + 4 * g);
    vxei4[t] = ld4(VXEP + ((size_t)((b * 16 + jti) * 4 + t)) * 256 + (g * 16 + r16i) * 4);
    sc4[t]   = ld4(ws + WS_ESUM + t * 16 + 4 * g);
    sh4[t]   = ld4(ws + WS_ESQ  + t * 16 + 4 * g);
  }

  float4 Ga[4], Gb[4];
  float4 Pj[2][4];
  load_tile_G(eTile, w, lane, 0, Ga);
  load_tile_G(eTile, w, lane, 1, Gb);
  {
    const size_t pb0 = (size_t)((b * 16 + (w * 4 + 0)) * 4);
#pragma unroll
    for (int t = 0; t < 4; ++t)
      Pj[0][t] = ld4(VXEP + (pb0 + t) * 256 + lane * 4);
  }
  __syncthreads();
  write_tile_L(myBuf, lane, 0, Ga);
  write_tile_L(myBuf, lane, 1, Gb);

#pragma unroll
  for (int p = 0; p < 4; ++p) {
    bf16x8 wF0[4], wF1[4];
#pragma unroll
    for (int t = 0; t < 4; ++t) {
      const int wr = (16 * t + r16) * 64;
      wF0[t] = *(const bf16x8*)(&wLds[wr + ((g ^ sw) << 3)]);
      wF1[t] = *(const bf16x8*)(&wLds[wr + (((4 + g) ^ sw) << 3)]);
    }
    const float* rbase = myBuf + (p & 1) * 1024 + r16 * 64;
    float4 f0 = ld4(rbase + (((2 * g)     ^ sw) << 2));
    float4 f1 = ld4(rbase + (((2 * g + 1) ^ sw) << 2));
    float4 f2 = ld4(rbase + ((((2 * g)     ^ sw) + 8) << 2));
    float4 f3 = ld4(rbase + ((((2 * g + 1) ^ sw) + 8) << 2));
    bf16x8 aF0 = cvt8(f0, f1);
    bf16x8 aF1 = cvt8(f2, f3);
    // residual rows for this phase (from LDS, before the buffer is rewritten)
    float4 res4[4];
#pragma unroll
    for (int t = 0; t < 4; ++t)
      res4[t] = ld4(rbase + (((4 * t + g) ^ sw) << 2));

    if (p < 3) {
      const size_t pbn = (size_t)((b * 16 + (w * 4 + p + 1)) * 4);
#pragma unroll
      for (int t = 0; t < 4; ++t)
        Pj[(p + 1) & 1][t] = ld4(VXEP + (pbn + t) * 256 + lane * 4);
    }
    if (p < 2) load_tile_G(eTile, w, lane, p + 2, (p & 1) ? Gb : Ga);

    f32x4 acc[4];
#pragma unroll
    for (int t = 0; t < 4; ++t) {
      f32x4 z = {0.f, 0.f, 0.f, 0.f};
      acc[t] = __builtin_amdgcn_mfma_f32_16x16x32_bf16(wF0[t], aF0, z, 0, 0, 0);
      acc[t] = __builtin_amdgcn_mfma_f32_16x16x32_bf16(wF1[t], aF1, acc[t], 0, 0, 0);
    }

    const int j = w * 64 + p * 16 + r16;
#pragma unroll
    for (int t = 0; t < 4; ++t) {
      float vj[4] = {Pj[p & 1][t].x, Pj[p & 1][t].y, Pj[p & 1][t].z, Pj[p & 1][t].w};
      float rs[4] = {res4[t].x, res4[t].y, res4[t].z, res4[t].w};
      float ub[4] = {ueb4[t].x, ueb4[t].y, ueb4[t].z, ueb4[t].w};
      float vi[4] = {vxei4[t].x, vxei4[t].y, vxei4[t].z, vxei4[t].w};
      float sc[4] = {sc4[t].x, sc4[t].y, sc4[t].z, sc4[t].w};
      float sh[4] = {sh4[t].x, sh4[t].y, sh4[t].z, sh4[t].w};
      float out[4];
#pragma unroll
      for (int r = 0; r < 4; ++r) {
        float tv = acc[t][r] + ub[r] + vi[r] + vj[r];
        float y  = fmaf(tv, sc[r], sh[r]);
        out[r] = fmaxf(y, 0.f) + rs[r];
      }
      *(float4*)(oTile + (size_t)j * 64 + t * 16 + 4 * g) =
          make_float4(out[0], out[1], out[2], out[3]);
    }

    if (p < 2) write_tile_L(myBuf, lane, p & 1, (p & 1) ? Gb : Ga);
    __builtin_amdgcn_sched_barrier(0);
  }
}

// ---------------------------------------------------------------------------
extern "C" void kernel_launch(void* const* d_in, const int* in_sizes, int n_in,
                              void* d_out, int out_size, void* d_ws, size_t ws_size,
                              hipStream_t stream)
{
  const float* x    = (const float*)d_in[0];
  const float* e    = (const float*)d_in[1];
  const float* UeW  = (const float*)d_in[2];
  const float* Ueb  = (const float*)d_in[3];
  const float* VeW  = (const float*)d_in[4];
  const float* Veb  = (const float*)d_in[5];
  const float* UnW  = (const float*)d_in[6];
  const float* Unb  = (const float*)d_in[7];
  const float* VnW  = (const float*)d_in[8];
  const float* Vnb  = (const float*)d_in[9];
  const float* bneg = (const float*)d_in[10];
  const float* bneb = (const float*)d_in[11];
  const float* bnng = (const float*)d_in[12];
  const float* bnnb = (const float*)d_in[13];

  float* ws   = (float*)d_ws;
  float* xOut = (float*)d_out;
  float* eOut = (float*)d_out + (size_t)ROWS * Hv;

  hipMemsetAsync(ws + WS_ESUM, 0, 128 * sizeof(float), stream);

  k_lin<<<128, 256, 0, stream>>>(x, VeW, Veb, UnW, Unb, VnW, Vnb, ws);
  k_edgeA<<<ROWS, 256, 0, stream>>>(e, UeW, Ueb, ws);
  k_node<<<Hv, 256, 0, stream>>>(x, bnng, bnnb, bneg, bneb, ws, xOut);
  k_edgeC<<<ROWS, 256, 0, stream>>>(e, UeW, Ueb, ws, eOut);
}